// Round 3
// baseline (2290.989 us; speedup 1.0000x reference)
//
#include <hip/hip_runtime.h>

#define NN     100000
#define EE     3200000
#define NF     512
#define HIDN   64
#define NCLS   64
#define ALPHA  0.1f

#define CHUNK  512                      // elements per scan block
#define NB     196                      // ceil(NN / CHUNK)

#define BSHIFT 7                        // 128 nodes per dst-bucket
#define NBUCK  782                      // ceil(NN / 128)

typedef unsigned short ushort_t;
typedef unsigned int   uint_t;

__device__ inline ushort_t f2bf(float f)   // fp32 -> bf16 RTN-even
{
    uint_t u = __float_as_uint(f);
    u += 0x7FFFu + ((u >> 16) & 1u);
    return (ushort_t)(u >> 16);
}
__device__ inline float bf2f(ushort_t b)
{
    return __uint_as_float(((uint_t)b) << 16);
}

// ---------------------------------------------------------------------------
// Tiled fp32 GEMM: C[nrows x 64] = act(A[nrows x K] @ B[K x 64])
// ---------------------------------------------------------------------------
template <bool RELU>
__global__ __launch_bounds__(256) void gemm_kernel(
    const float* __restrict__ A, const float* __restrict__ B,
    float* __restrict__ C, int nrows, int K)
{
    const int BK = 16;
    __shared__ float AsT[BK][68];
    __shared__ float Bs [BK][68];

    int tid = threadIdx.x;
    int tx  = tid & 15;
    int ty  = tid >> 4;
    int rowBase = blockIdx.x * 64;

    int arow = tid >> 2;
    int ak   = (tid & 3) * 4;
    int brow = tid >> 4;
    int bcol = (tid & 15) * 4;

    float acc[4][4] = {};

    for (int k0 = 0; k0 < K; k0 += BK) {
        float4 av;
        int gr = rowBase + arow;
        if (gr < nrows) av = *(const float4*)(A + (size_t)gr * K + k0 + ak);
        else            av = make_float4(0.f, 0.f, 0.f, 0.f);
        float4 bv = *(const float4*)(B + (size_t)(k0 + brow) * 64 + bcol);

        __syncthreads();
        AsT[ak + 0][arow] = av.x;
        AsT[ak + 1][arow] = av.y;
        AsT[ak + 2][arow] = av.z;
        AsT[ak + 3][arow] = av.w;
        *(float4*)&Bs[brow][bcol] = bv;
        __syncthreads();

#pragma unroll
        for (int kk = 0; kk < BK; ++kk) {
            float4 a = *(const float4*)&AsT[kk][ty * 4];
            float4 b = *(const float4*)&Bs [kk][tx * 4];
            acc[0][0] = fmaf(a.x, b.x, acc[0][0]);
            acc[0][1] = fmaf(a.x, b.y, acc[0][1]);
            acc[0][2] = fmaf(a.x, b.z, acc[0][2]);
            acc[0][3] = fmaf(a.x, b.w, acc[0][3]);
            acc[1][0] = fmaf(a.y, b.x, acc[1][0]);
            acc[1][1] = fmaf(a.y, b.y, acc[1][1]);
            acc[1][2] = fmaf(a.y, b.z, acc[1][2]);
            acc[1][3] = fmaf(a.y, b.w, acc[1][3]);
            acc[2][0] = fmaf(a.z, b.x, acc[2][0]);
            acc[2][1] = fmaf(a.z, b.y, acc[2][1]);
            acc[2][2] = fmaf(a.z, b.z, acc[2][2]);
            acc[2][3] = fmaf(a.z, b.w, acc[2][3]);
            acc[3][0] = fmaf(a.w, b.x, acc[3][0]);
            acc[3][1] = fmaf(a.w, b.y, acc[3][1]);
            acc[3][2] = fmaf(a.w, b.z, acc[3][2]);
            acc[3][3] = fmaf(a.w, b.w, acc[3][3]);
        }
    }

#pragma unroll
    for (int i = 0; i < 4; ++i) {
        int r = rowBase + ty * 4 + i;
        if (r < nrows) {
            float4 o;
            o.x = acc[i][0]; o.y = acc[i][1]; o.z = acc[i][2]; o.w = acc[i][3];
            if (RELU) {
                o.x = fmaxf(o.x, 0.f); o.y = fmaxf(o.y, 0.f);
                o.z = fmaxf(o.z, 0.f); o.w = fmaxf(o.w, 0.f);
            }
            *(float4*)(C + (size_t)r * 64 + tx * 4) = o;
        }
    }
}

// ---------------------------------------------------------------------------
// CSR construction
// ---------------------------------------------------------------------------
__global__ __launch_bounds__(256) void zero_kernel(int* __restrict__ p, int n)
{
    int i = blockIdx.x * 256 + threadIdx.x;
    if (i < n) p[i] = 0;
}

__global__ __launch_bounds__(256) void count_kernel(const int* __restrict__ dst,
                                                    int* __restrict__ deg)
{
    int e = blockIdx.x * 256 + threadIdx.x;
    if (e < EE) atomicAdd(&deg[dst[e]], 1);
}

__global__ __launch_bounds__(256) void scanA_kernel(const int* __restrict__ deg,
                                                    int* __restrict__ bsum)
{
    int b = blockIdx.x, t = threadIdx.x;
    int i = b * CHUNK + t * 2;
    int v = 0;
    if (i < NN)     v += deg[i];
    if (i + 1 < NN) v += deg[i + 1];
    __shared__ int sm[256];
    sm[t] = v;
    __syncthreads();
    for (int o = 128; o > 0; o >>= 1) {
        if (t < o) sm[t] += sm[t + o];
        __syncthreads();
    }
    if (t == 0) bsum[b] = sm[0];
}

__global__ __launch_bounds__(256) void scanB_kernel(const int* __restrict__ bsum,
                                                    int* __restrict__ bbase,
                                                    int* __restrict__ offs)
{
    int t = threadIdx.x;
    int v = (t < NB) ? bsum[t] : 0;
    __shared__ int sm[256];
    sm[t] = v;
    __syncthreads();
    for (int o = 1; o < 256; o <<= 1) {
        int u = (t >= o) ? sm[t - o] : 0;
        __syncthreads();
        sm[t] += u;
        __syncthreads();
    }
    if (t < NB) bbase[t] = sm[t] - v;
    if (t == 0) offs[NN] = EE;
}

__global__ __launch_bounds__(256) void scanC_kernel(const int* __restrict__ deg,
                                                    const int* __restrict__ bbase,
                                                    int* __restrict__ offs,
                                                    int* __restrict__ cursor)
{
    int b = blockIdx.x, t = threadIdx.x;
    int i0 = b * CHUNK + t * 2;
    int d0 = (i0 < NN)     ? deg[i0]     : 0;
    int d1 = (i0 + 1 < NN) ? deg[i0 + 1] : 0;
    int local = d0 + d1;
    __shared__ int sm[256];
    sm[t] = local;
    __syncthreads();
    for (int o = 1; o < 256; o <<= 1) {
        int u = (t >= o) ? sm[t - o] : 0;
        __syncthreads();
        sm[t] += u;
        __syncthreads();
    }
    int excl = sm[t] - local + bbase[b];
    if (i0 < NN)     { offs[i0]     = excl;      cursor[i0]     = excl;      }
    if (i0 + 1 < NN) { offs[i0 + 1] = excl + d0; cursor[i0 + 1] = excl + d0; }
}

// bucket cursors: bcur[b] = offs[first node of bucket b]
__global__ __launch_bounds__(256) void bcur_kernel(const int* __restrict__ offs,
                                                   int* __restrict__ bcur)
{
    int b = blockIdx.x * 256 + threadIdx.x;
    if (b < NBUCK) {
        int n = b << BSHIFT;
        bcur[b] = offs[n < NN ? n : NN];
    }
}

// pass 1: append edges into dst-range buckets (sequential appends, no 8x blowup)
// entry.x = src | (dstLocal << 17), entry.y = weight bits
__global__ __launch_bounds__(256) void bucketize_kernel(
    const int* __restrict__ src, const int* __restrict__ dst,
    const float* __restrict__ w, int* bcur, int2* __restrict__ tA)
{
    int e = blockIdx.x * 256 + threadIdx.x;
    if (e >= EE) return;
    int d = dst[e];
    int b = d >> BSHIFT;
    int pos = atomicAdd(&bcur[b], 1);
    tA[pos] = make_int2(src[e] | ((d & ((1 << BSHIFT) - 1)) << 17),
                        __float_as_int(w[e]));
}

// pass 2: place bucket edges into final per-node CSR slots (32 KB window/block)
__global__ __launch_bounds__(256) void place_kernel(
    const int2* __restrict__ tA, const int* __restrict__ offs,
    int* cursor, int2* __restrict__ csr)
{
    int b  = blockIdx.x;
    int n0 = b << BSHIFT;
    int n1 = (b + 1) << BSHIFT; if (n1 > NN) n1 = NN;
    int base = offs[n0];
    int end  = offs[n1];
    for (int i = base + threadIdx.x; i < end; i += 256) {
        int2 e = tA[i];
        int d = n0 + (e.x >> 17);
        int pos = atomicAdd(&cursor[d], 1);
        csr[pos] = make_int2(e.x & 0x1FFFF, e.y);
    }
}

// z0 (fp32) -> zb (bf16), vectorized
__global__ __launch_bounds__(256) void cvt_kernel(const float* __restrict__ z0,
                                                  ushort_t* __restrict__ zb)
{
    int i = (blockIdx.x * 256 + threadIdx.x) * 4;
    if (i >= NN * 64) return;
    float4 v = *(const float4*)(z0 + i);
    ushort4 o;
    o.x = f2bf(v.x); o.y = f2bf(v.y); o.z = f2bf(v.z); o.w = f2bf(v.w);
    *(ushort4*)(zb + i) = o;
}

// ---------------------------------------------------------------------------
// APPNP propagation: one wave per dst node, lane = class. bf16 z, fp32 acc.
// ---------------------------------------------------------------------------
template <bool LSM>
__global__ __launch_bounds__(256) void propagate_kernel(
    const ushort_t* __restrict__ zin, const float* __restrict__ z0,
    ushort_t* __restrict__ zout_b, float* __restrict__ zout_f,
    const int* __restrict__ offs, const int2* __restrict__ csr)
{
    int gid  = blockIdx.x * 256 + threadIdx.x;
    int node = gid >> 6;
    int lane = gid & 63;
    if (node >= NN) return;

    int beg = offs[node];
    int end = offs[node + 1];
    float acc = 0.f;
    int j = beg;
    for (; j + 8 <= end; j += 8) {
        int2 e0 = csr[j],     e1 = csr[j + 1], e2 = csr[j + 2], e3 = csr[j + 3];
        int2 e4 = csr[j + 4], e5 = csr[j + 5], e6 = csr[j + 6], e7 = csr[j + 7];
        float v0 = bf2f(zin[(size_t)e0.x * 64 + lane]);
        float v1 = bf2f(zin[(size_t)e1.x * 64 + lane]);
        float v2 = bf2f(zin[(size_t)e2.x * 64 + lane]);
        float v3 = bf2f(zin[(size_t)e3.x * 64 + lane]);
        float v4 = bf2f(zin[(size_t)e4.x * 64 + lane]);
        float v5 = bf2f(zin[(size_t)e5.x * 64 + lane]);
        float v6 = bf2f(zin[(size_t)e6.x * 64 + lane]);
        float v7 = bf2f(zin[(size_t)e7.x * 64 + lane]);
        acc = fmaf(__int_as_float(e0.y), v0, acc);
        acc = fmaf(__int_as_float(e1.y), v1, acc);
        acc = fmaf(__int_as_float(e2.y), v2, acc);
        acc = fmaf(__int_as_float(e3.y), v3, acc);
        acc = fmaf(__int_as_float(e4.y), v4, acc);
        acc = fmaf(__int_as_float(e5.y), v5, acc);
        acc = fmaf(__int_as_float(e6.y), v6, acc);
        acc = fmaf(__int_as_float(e7.y), v7, acc);
    }
    for (; j < end; ++j) {
        int2 e = csr[j];
        acc = fmaf(__int_as_float(e.y), bf2f(zin[(size_t)e.x * 64 + lane]), acc);
    }

    float out = fmaf(ALPHA, z0[(size_t)node * 64 + lane], acc);

    if (LSM) {
        float m = out;
#pragma unroll
        for (int o = 32; o > 0; o >>= 1) m = fmaxf(m, __shfl_xor(m, o, 64));
        float e = __expf(out - m);
        float s = e;
#pragma unroll
        for (int o = 32; o > 0; o >>= 1) s += __shfl_xor(s, o, 64);
        zout_f[(size_t)node * 64 + lane] = (out - m) - __logf(s);
    } else {
        zout_b[(size_t)node * 64 + lane] = f2bf(out);
    }
}

// ---------------------------------------------------------------------------
extern "C" void kernel_launch(void* const* d_in, const int* in_sizes, int n_in,
                              void* d_out, int out_size, void* d_ws, size_t ws_size,
                              hipStream_t stream)
{
    const float* x  = (const float*)d_in[0];
    const int*   ei = (const int*)  d_in[1];
    const float* ew = (const float*)d_in[2];
    const float* W1 = (const float*)d_in[3];
    const float* W2 = (const float*)d_in[4];
    const int* src = ei;
    const int* dst = ei + EE;

    char* ws = (char*)d_ws;
    size_t off = 0;
    auto alloc = [&](size_t bytes) -> char* {
        char* p = ws + off;
        off += (bytes + 255) & ~(size_t)255;
        return p;
    };

    float*    h     = (float*)   alloc((size_t)NN * HIDN * 4);  // 25.6 MB; -> csr
    float*    z0    = (float*)   alloc((size_t)NN * NCLS * 4);  // 25.6 MB
    ushort_t* zbA   = (ushort_t*)alloc((size_t)NN * NCLS * 2);  // 12.8 MB }-> tA aliases
    ushort_t* zbB   = (ushort_t*)alloc((size_t)NN * NCLS * 2);  // 12.8 MB }   both
    int*      deg   = (int*)     alloc((size_t)NN * 4);
    int*      offs  = (int*)     alloc((size_t)(NN + 1) * 4);
    int*      cur_  = (int*)     alloc((size_t)NN * 4);
    int*      bsum  = (int*)     alloc((size_t)NB * 4);
    int*      bbase = (int*)     alloc((size_t)NB * 4);
    int*      bcur  = (int*)     alloc((size_t)NBUCK * 4);

    int2* csr = (int2*)h;       // h dead after GEMM2
    int2* tA  = (int2*)zbA;     // zbA/zbB not live until after place_kernel

    // feature transform
    gemm_kernel<true ><<<(NN + 63) / 64, 256, 0, stream>>>(x, W1, h, NN, NF);
    gemm_kernel<false><<<(NN + 63) / 64, 256, 0, stream>>>(h, W2, z0, NN, HIDN);

    // CSR build (bucketed two-pass, low write amplification)
    zero_kernel<<<(NN + 255) / 256, 256, 0, stream>>>(deg, NN);
    count_kernel<<<EE / 256, 256, 0, stream>>>(dst, deg);
    scanA_kernel<<<NB, 256, 0, stream>>>(deg, bsum);
    scanB_kernel<<<1, 256, 0, stream>>>(bsum, bbase, offs);
    scanC_kernel<<<NB, 256, 0, stream>>>(deg, bbase, offs, cur_);
    bcur_kernel<<<(NBUCK + 255) / 256, 256, 0, stream>>>(offs, bcur);
    bucketize_kernel<<<EE / 256, 256, 0, stream>>>(src, dst, ew, bcur, tA);
    place_kernel<<<NBUCK, 256, 0, stream>>>(tA, offs, cur_, csr);

    // z = z0 in bf16 (after tA is dead)
    cvt_kernel<<<(NN * 64 / 4 + 255) / 256, 256, 0, stream>>>(z0, zbA);

    // 10 power iterations, bf16 ping-pong; final emits fp32 log_softmax
    const ushort_t* cur = zbA;
    ushort_t* nxt = zbB;
    for (int it = 0; it < 9; ++it) {
        propagate_kernel<false><<<(NN * 64) / 256, 256, 0, stream>>>(
            cur, z0, nxt, nullptr, offs, csr);
        ushort_t* t = (ushort_t*)cur; cur = nxt; nxt = t;
    }
    propagate_kernel<true><<<(NN * 64) / 256, 256, 0, stream>>>(
        cur, z0, nullptr, (float*)d_out, offs, csr);
}

// Round 4
// 1607.638 us; speedup vs baseline: 1.4251x; 1.4251x over previous
//
#include <hip/hip_runtime.h>

#define NN     100000
#define EE     3200000
#define NF     512
#define HIDN   64
#define NCLS   64
#define ALPHA  0.1f

#define CHUNK  512                      // elements per scan block
#define NB     196                      // ceil(NN / CHUNK)

typedef unsigned short ushort_t;
typedef unsigned int   uint_t;

__device__ inline ushort_t f2bf(float f)   // fp32 -> bf16 RTN-even
{
    uint_t u = __float_as_uint(f);
    u += 0x7FFFu + ((u >> 16) & 1u);
    return (ushort_t)(u >> 16);
}
__device__ inline float bf2f(ushort_t b)
{
    return __uint_as_float(((uint_t)b) << 16);
}

// ---------------------------------------------------------------------------
// Tiled fp32 GEMM: C[nrows x 64] = act(A[nrows x K] @ B[K x 64])
// ---------------------------------------------------------------------------
template <bool RELU>
__global__ __launch_bounds__(256) void gemm_kernel(
    const float* __restrict__ A, const float* __restrict__ B,
    float* __restrict__ C, int nrows, int K)
{
    const int BK = 16;
    __shared__ float AsT[BK][68];
    __shared__ float Bs [BK][68];

    int tid = threadIdx.x;
    int tx  = tid & 15;
    int ty  = tid >> 4;
    int rowBase = blockIdx.x * 64;

    int arow = tid >> 2;
    int ak   = (tid & 3) * 4;
    int brow = tid >> 4;
    int bcol = (tid & 15) * 4;

    float acc[4][4] = {};

    for (int k0 = 0; k0 < K; k0 += BK) {
        float4 av;
        int gr = rowBase + arow;
        if (gr < nrows) av = *(const float4*)(A + (size_t)gr * K + k0 + ak);
        else            av = make_float4(0.f, 0.f, 0.f, 0.f);
        float4 bv = *(const float4*)(B + (size_t)(k0 + brow) * 64 + bcol);

        __syncthreads();
        AsT[ak + 0][arow] = av.x;
        AsT[ak + 1][arow] = av.y;
        AsT[ak + 2][arow] = av.z;
        AsT[ak + 3][arow] = av.w;
        *(float4*)&Bs[brow][bcol] = bv;
        __syncthreads();

#pragma unroll
        for (int kk = 0; kk < BK; ++kk) {
            float4 a = *(const float4*)&AsT[kk][ty * 4];
            float4 b = *(const float4*)&Bs [kk][tx * 4];
            acc[0][0] = fmaf(a.x, b.x, acc[0][0]);
            acc[0][1] = fmaf(a.x, b.y, acc[0][1]);
            acc[0][2] = fmaf(a.x, b.z, acc[0][2]);
            acc[0][3] = fmaf(a.x, b.w, acc[0][3]);
            acc[1][0] = fmaf(a.y, b.x, acc[1][0]);
            acc[1][1] = fmaf(a.y, b.y, acc[1][1]);
            acc[1][2] = fmaf(a.y, b.z, acc[1][2]);
            acc[1][3] = fmaf(a.y, b.w, acc[1][3]);
            acc[2][0] = fmaf(a.z, b.x, acc[2][0]);
            acc[2][1] = fmaf(a.z, b.y, acc[2][1]);
            acc[2][2] = fmaf(a.z, b.z, acc[2][2]);
            acc[2][3] = fmaf(a.z, b.w, acc[2][3]);
            acc[3][0] = fmaf(a.w, b.x, acc[3][0]);
            acc[3][1] = fmaf(a.w, b.y, acc[3][1]);
            acc[3][2] = fmaf(a.w, b.z, acc[3][2]);
            acc[3][3] = fmaf(a.w, b.w, acc[3][3]);
        }
    }

#pragma unroll
    for (int i = 0; i < 4; ++i) {
        int r = rowBase + ty * 4 + i;
        if (r < nrows) {
            float4 o;
            o.x = acc[i][0]; o.y = acc[i][1]; o.z = acc[i][2]; o.w = acc[i][3];
            if (RELU) {
                o.x = fmaxf(o.x, 0.f); o.y = fmaxf(o.y, 0.f);
                o.z = fmaxf(o.z, 0.f); o.w = fmaxf(o.w, 0.f);
            }
            *(float4*)(C + (size_t)r * 64 + tx * 4) = o;
        }
    }
}

// ---------------------------------------------------------------------------
// CSR construction (round-2 proven pipeline: per-node cursors, low contention)
// ---------------------------------------------------------------------------
__global__ __launch_bounds__(256) void zero_kernel(int* __restrict__ p, int n)
{
    int i = blockIdx.x * 256 + threadIdx.x;
    if (i < n) p[i] = 0;
}

__global__ __launch_bounds__(256) void count_kernel(const int* __restrict__ dst,
                                                    int* __restrict__ deg)
{
    int e = blockIdx.x * 256 + threadIdx.x;
    if (e < EE) atomicAdd(&deg[dst[e]], 1);
}

__global__ __launch_bounds__(256) void scanA_kernel(const int* __restrict__ deg,
                                                    int* __restrict__ bsum)
{
    int b = blockIdx.x, t = threadIdx.x;
    int i = b * CHUNK + t * 2;
    int v = 0;
    if (i < NN)     v += deg[i];
    if (i + 1 < NN) v += deg[i + 1];
    __shared__ int sm[256];
    sm[t] = v;
    __syncthreads();
    for (int o = 128; o > 0; o >>= 1) {
        if (t < o) sm[t] += sm[t + o];
        __syncthreads();
    }
    if (t == 0) bsum[b] = sm[0];
}

__global__ __launch_bounds__(256) void scanB_kernel(const int* __restrict__ bsum,
                                                    int* __restrict__ bbase,
                                                    int* __restrict__ offs)
{
    int t = threadIdx.x;
    int v = (t < NB) ? bsum[t] : 0;
    __shared__ int sm[256];
    sm[t] = v;
    __syncthreads();
    for (int o = 1; o < 256; o <<= 1) {
        int u = (t >= o) ? sm[t - o] : 0;
        __syncthreads();
        sm[t] += u;
        __syncthreads();
    }
    if (t < NB) bbase[t] = sm[t] - v;
    if (t == 0) offs[NN] = EE;
}

__global__ __launch_bounds__(256) void scanC_kernel(const int* __restrict__ deg,
                                                    const int* __restrict__ bbase,
                                                    int* __restrict__ offs,
                                                    int* __restrict__ cursor)
{
    int b = blockIdx.x, t = threadIdx.x;
    int i0 = b * CHUNK + t * 2;
    int d0 = (i0 < NN)     ? deg[i0]     : 0;
    int d1 = (i0 + 1 < NN) ? deg[i0 + 1] : 0;
    int local = d0 + d1;
    __shared__ int sm[256];
    sm[t] = local;
    __syncthreads();
    for (int o = 1; o < 256; o <<= 1) {
        int u = (t >= o) ? sm[t - o] : 0;
        __syncthreads();
        sm[t] += u;
        __syncthreads();
    }
    int excl = sm[t] - local + bbase[b];
    if (i0 < NN)     { offs[i0]     = excl;      cursor[i0]     = excl;      }
    if (i0 + 1 < NN) { offs[i0 + 1] = excl + d0; cursor[i0 + 1] = excl + d0; }
}

__global__ __launch_bounds__(256) void scatter_kernel(
    const int* __restrict__ src, const int* __restrict__ dst,
    const float* __restrict__ w, int* cursor, int2* __restrict__ csr)
{
    int e = blockIdx.x * 256 + threadIdx.x;
    if (e >= EE) return;
    int d = dst[e];
    int pos = atomicAdd(&cursor[d], 1);
    csr[pos] = make_int2(src[e], __float_as_int(w[e]));
}

// z0 (fp32) -> zb (bf16), vectorized
__global__ __launch_bounds__(256) void cvt_kernel(const float* __restrict__ z0,
                                                  ushort_t* __restrict__ zb)
{
    int i = (blockIdx.x * 256 + threadIdx.x) * 4;
    if (i >= NN * 64) return;
    float4 v = *(const float4*)(z0 + i);
    ushort4 o;
    o.x = f2bf(v.x); o.y = f2bf(v.y); o.z = f2bf(v.z); o.w = f2bf(v.w);
    *(ushort4*)(zb + i) = o;
}

// ---------------------------------------------------------------------------
// APPNP propagation: one wave per dst node, lane = class. bf16 z, fp32 acc.
// ---------------------------------------------------------------------------
template <bool LSM>
__global__ __launch_bounds__(256) void propagate_kernel(
    const ushort_t* __restrict__ zin, const float* __restrict__ z0,
    ushort_t* __restrict__ zout_b, float* __restrict__ zout_f,
    const int* __restrict__ offs, const int2* __restrict__ csr)
{
    int gid  = blockIdx.x * 256 + threadIdx.x;
    int node = gid >> 6;
    int lane = gid & 63;
    if (node >= NN) return;

    int beg = offs[node];
    int end = offs[node + 1];
    float acc = 0.f;
    int j = beg;
    for (; j + 8 <= end; j += 8) {
        int2 e0 = csr[j],     e1 = csr[j + 1], e2 = csr[j + 2], e3 = csr[j + 3];
        int2 e4 = csr[j + 4], e5 = csr[j + 5], e6 = csr[j + 6], e7 = csr[j + 7];
        float v0 = bf2f(zin[(size_t)e0.x * 64 + lane]);
        float v1 = bf2f(zin[(size_t)e1.x * 64 + lane]);
        float v2 = bf2f(zin[(size_t)e2.x * 64 + lane]);
        float v3 = bf2f(zin[(size_t)e3.x * 64 + lane]);
        float v4 = bf2f(zin[(size_t)e4.x * 64 + lane]);
        float v5 = bf2f(zin[(size_t)e5.x * 64 + lane]);
        float v6 = bf2f(zin[(size_t)e6.x * 64 + lane]);
        float v7 = bf2f(zin[(size_t)e7.x * 64 + lane]);
        acc = fmaf(__int_as_float(e0.y), v0, acc);
        acc = fmaf(__int_as_float(e1.y), v1, acc);
        acc = fmaf(__int_as_float(e2.y), v2, acc);
        acc = fmaf(__int_as_float(e3.y), v3, acc);
        acc = fmaf(__int_as_float(e4.y), v4, acc);
        acc = fmaf(__int_as_float(e5.y), v5, acc);
        acc = fmaf(__int_as_float(e6.y), v6, acc);
        acc = fmaf(__int_as_float(e7.y), v7, acc);
    }
    for (; j < end; ++j) {
        int2 e = csr[j];
        acc = fmaf(__int_as_float(e.y), bf2f(zin[(size_t)e.x * 64 + lane]), acc);
    }

    float out = fmaf(ALPHA, z0[(size_t)node * 64 + lane], acc);

    if (LSM) {
        float m = out;
#pragma unroll
        for (int o = 32; o > 0; o >>= 1) m = fmaxf(m, __shfl_xor(m, o, 64));
        float e = __expf(out - m);
        float s = e;
#pragma unroll
        for (int o = 32; o > 0; o >>= 1) s += __shfl_xor(s, o, 64);
        zout_f[(size_t)node * 64 + lane] = (out - m) - __logf(s);
    } else {
        zout_b[(size_t)node * 64 + lane] = f2bf(out);
    }
}

// ---------------------------------------------------------------------------
extern "C" void kernel_launch(void* const* d_in, const int* in_sizes, int n_in,
                              void* d_out, int out_size, void* d_ws, size_t ws_size,
                              hipStream_t stream)
{
    const float* x  = (const float*)d_in[0];
    const int*   ei = (const int*)  d_in[1];
    const float* ew = (const float*)d_in[2];
    const float* W1 = (const float*)d_in[3];
    const float* W2 = (const float*)d_in[4];
    const int* src = ei;
    const int* dst = ei + EE;

    char* ws = (char*)d_ws;
    size_t off = 0;
    auto alloc = [&](size_t bytes) -> char* {
        char* p = ws + off;
        off += (bytes + 255) & ~(size_t)255;
        return p;
    };

    float*    h     = (float*)   alloc((size_t)NN * HIDN * 4);  // 25.6 MB; -> csr
    float*    z0    = (float*)   alloc((size_t)NN * NCLS * 4);  // 25.6 MB
    ushort_t* zbA   = (ushort_t*)alloc((size_t)NN * NCLS * 2);  // 12.8 MB
    ushort_t* zbB   = (ushort_t*)alloc((size_t)NN * NCLS * 2);  // 12.8 MB
    int*      deg   = (int*)     alloc((size_t)NN * 4);
    int*      offs  = (int*)     alloc((size_t)(NN + 1) * 4);
    int*      cur_  = (int*)     alloc((size_t)NN * 4);
    int*      bsum  = (int*)     alloc((size_t)NB * 4);
    int*      bbase = (int*)     alloc((size_t)NB * 4);

    int2* csr = (int2*)h;       // h dead after GEMM2

    // feature transform
    gemm_kernel<true ><<<(NN + 63) / 64, 256, 0, stream>>>(x, W1, h, NN, NF);
    gemm_kernel<false><<<(NN + 63) / 64, 256, 0, stream>>>(h, W2, z0, NN, HIDN);

    // CSR build (round-2 scatter: 100K cursors -> negligible atomic contention)
    zero_kernel<<<(NN + 255) / 256, 256, 0, stream>>>(deg, NN);
    count_kernel<<<EE / 256, 256, 0, stream>>>(dst, deg);
    scanA_kernel<<<NB, 256, 0, stream>>>(deg, bsum);
    scanB_kernel<<<1, 256, 0, stream>>>(bsum, bbase, offs);
    scanC_kernel<<<NB, 256, 0, stream>>>(deg, bbase, offs, cur_);
    scatter_kernel<<<EE / 256, 256, 0, stream>>>(src, dst, ew, cur_, csr);

    // z = z0 in bf16
    cvt_kernel<<<(NN * 64 / 4 + 255) / 256, 256, 0, stream>>>(z0, zbA);

    // 10 power iterations, bf16 ping-pong; final emits fp32 log_softmax
    const ushort_t* cur = zbA;
    ushort_t* nxt = zbB;
    for (int it = 0; it < 9; ++it) {
        propagate_kernel<false><<<(NN * 64) / 256, 256, 0, stream>>>(
            cur, z0, nxt, nullptr, offs, csr);
        ushort_t* t = (ushort_t*)cur; cur = nxt; nxt = t;
    }
    propagate_kernel<true><<<(NN * 64) / 256, 256, 0, stream>>>(
        cur, z0, nullptr, (float*)d_out, offs, csr);
}